// Round 5
// baseline (450.675 us; speedup 1.0000x reference)
//
#include <hip/hip_runtime.h>
#include <hip/hip_bf16.h>
#include <math.h>

// GanDTI forward. B=4096, N_ATOMS=50, FEAT=40, GNN_DEPTH=3, MLP_DEPTH=2.
//
// k_heavy: 5120 blocks x 256 threads.
//   blocks [0,1024):   A69 [B*1001 rows][30] streaming dot with W1 -> ws_a69
//                      (grid-stride, pure HBM stream, overlaps GNN)
//   blocks [1024,5120): GNN, one sample/block. LDS holds ONLY comp+h (17.6KB);
//                      Wg and A are read from global (L1/L2) to cut LDS-port load.
// k_tail: 512 blocks x 256 threads, 8 samples/block.
//   a256 = a69 @ W2 (chunk-staged LDS + register acc), p256 in registers,
//   then p40 / attention / MLP head.

#define BATCH 4096
#define SC 44              // comp/h row stride (floats)
#define R_TOT 4100096      // 4096*1001
#define T_STR 262144       // 1024*256 streaming threads

__global__ __launch_bounds__(256) void k_heavy(
    const int* __restrict__ atoms, const float* __restrict__ A,
    const float* __restrict__ A69, const float* __restrict__ emb,
    const float* __restrict__ Wg, const float* __restrict__ bg,
    const float* __restrict__ W1, const float* __restrict__ b1,
    float* __restrict__ ws_cv, float* __restrict__ ws_a69)
{
    __shared__ float sm[4400];   // comp [50][44] + h [50][44]
    const int tid = threadIdx.x;
    const int blk = blockIdx.x;

    if (blk < 1024) {
        // ================= A69 row stream: a69[r] = A69[r,:] . W1 + b1 =================
        float w1r[30];
        #pragma unroll
        for (int k = 0; k < 15; ++k) {
            float2 t = ((const float2*)W1)[k];
            w1r[2 * k] = t.x; w1r[2 * k + 1] = t.y;
        }
        const float b1v = b1[0];
        const int t0 = (blk << 8) + tid;
        for (size_t r = t0; r < (size_t)R_TOT; r += T_STR) {
            const float2* p = (const float2*)(A69 + r * 30);
            float v = b1v;
            #pragma unroll
            for (int k = 0; k < 15; ++k) {
                float2 q = p[k];
                v = fmaf(q.x, w1r[2 * k], v);
                v = fmaf(q.y, w1r[2 * k + 1], v);
            }
            ws_a69[r] = v;
        }
    } else {
        // ================= GNN: one sample per block =================
        const int b = blk - 1024;
        float* comp = sm;          // [50][SC]
        float* h_s  = sm + 2200;   // [50][SC]

        // stage emb -> comp (b128)
        for (int idx = tid; idx < 500; idx += 256) {
            const int n = idx / 10, f4 = idx - n * 10;
            const int row = atoms[b * 50 + n];
            *(float4*)(comp + n * SC + f4 * 4) = *(const float4*)(emb + row * 40 + f4 * 4);
        }
        __syncthreads();

        float res_sum = 0.f;
        if (tid < 40) {
            for (int n = 0; n < 50; ++n) res_sum += comp[n * SC + tid];
        }

        const int np = tid / 10, fg = tid - np * 10;
        const int n0 = np * 2, f0 = fg * 4;
        const bool act = (tid < 250);
        const float* Arow0 = A + (size_t)b * 2500 + n0 * 50;  // row n0 (16B-aligned)

        for (int l = 0; l < 3; ++l) {
            const float* wgl = Wg + l * 1600;
            if (act) {
                // ---- m1: h = leaky(comp @ Wg[l] + bg[l]) ----
                float bgv[4];
                *(float4*)bgv = *(const float4*)(bg + l * 40 + f0);
                float acc0[4] = {bgv[0], bgv[1], bgv[2], bgv[3]};
                float acc1[4] = {bgv[0], bgv[1], bgv[2], bgv[3]};
                #pragma unroll
                for (int j4 = 0; j4 < 10; ++j4) {
                    float c0a[4], c1a[4];
                    *(float4*)c0a = *(float4*)(comp + n0 * SC + j4 * 4);
                    *(float4*)c1a = *(float4*)(comp + n0 * SC + SC + j4 * 4);
                    #pragma unroll
                    for (int u = 0; u < 4; ++u) {
                        float wv[4];
                        *(float4*)wv = *(const float4*)(wgl + (j4 * 4 + u) * 40 + f0);
                        #pragma unroll
                        for (int q = 0; q < 4; ++q) {
                            acc0[q] = fmaf(c0a[u], wv[q], acc0[q]);
                            acc1[q] = fmaf(c1a[u], wv[q], acc1[q]);
                        }
                    }
                }
                float h0[4], h1[4];
                #pragma unroll
                for (int q = 0; q < 4; ++q) {
                    h0[q] = acc0[q] > 0.f ? acc0[q] : 0.01f * acc0[q];
                    h1[q] = acc1[q] > 0.f ? acc1[q] : 0.01f * acc1[q];
                }
                *(float4*)(h_s + n0 * SC + f0) = *(float4*)h0;
                *(float4*)(h_s + n0 * SC + SC + f0) = *(float4*)h1;
            }
            __syncthreads();
            // ---- m2: comp += A @ h (A from global; row n0 b128, row n0+1 b64) ----
            if (act) {
                float acc0[4] = {0, 0, 0, 0}, acc1[4] = {0, 0, 0, 0};
                #pragma unroll
                for (int m4 = 0; m4 < 12; ++m4) {
                    float a0a[4], a1a[4];
                    *(float4*)a0a       = *(const float4*)(Arow0 + m4 * 4);
                    *(float2*)a1a       = *(const float2*)(Arow0 + 50 + m4 * 4);
                    *(float2*)(a1a + 2) = *(const float2*)(Arow0 + 50 + m4 * 4 + 2);
                    #pragma unroll
                    for (int u = 0; u < 4; ++u) {
                        float hv[4];
                        *(float4*)hv = *(float4*)(h_s + (m4 * 4 + u) * SC + f0);
                        #pragma unroll
                        for (int q = 0; q < 4; ++q) {
                            acc0[q] = fmaf(a0a[u], hv[q], acc0[q]);
                            acc1[q] = fmaf(a1a[u], hv[q], acc1[q]);
                        }
                    }
                }
                {   // tail m = 48, 49
                    float2 at0 = *(const float2*)(Arow0 + 48);
                    float2 at1 = *(const float2*)(Arow0 + 50 + 48);
                    float h48[4], h49[4];
                    *(float4*)h48 = *(float4*)(h_s + 48 * SC + f0);
                    *(float4*)h49 = *(float4*)(h_s + 49 * SC + f0);
                    #pragma unroll
                    for (int q = 0; q < 4; ++q) {
                        acc0[q] = fmaf(at0.x, h48[q], acc0[q]);
                        acc0[q] = fmaf(at0.y, h49[q], acc0[q]);
                        acc1[q] = fmaf(at1.x, h48[q], acc1[q]);
                        acc1[q] = fmaf(at1.y, h49[q], acc1[q]);
                    }
                }
                float c0a[4], c1a[4];
                *(float4*)c0a = *(float4*)(comp + n0 * SC + f0);
                *(float4*)c1a = *(float4*)(comp + n0 * SC + SC + f0);
                #pragma unroll
                for (int q = 0; q < 4; ++q) { c0a[q] += acc0[q]; c1a[q] += acc1[q]; }
                *(float4*)(comp + n0 * SC + f0) = *(float4*)c0a;
                *(float4*)(comp + n0 * SC + SC + f0) = *(float4*)c1a;
            }
            __syncthreads();
        }
        if (tid < 40) {
            float s = res_sum;
            for (int n = 0; n < 50; ++n) s += comp[n * SC + tid];
            ws_cv[(size_t)b * 40 + tid] = s * 0.02f;
        }
    }
}

__global__ __launch_bounds__(256) void k_tail(
    const float* __restrict__ protein,
    const float* __restrict__ W2, const float* __restrict__ b2,
    const float* __restrict__ W3, const float* __restrict__ b3,
    const float* __restrict__ Wp, const float* __restrict__ bp,
    const float* __restrict__ Watt, const float* __restrict__ batt,
    const float* __restrict__ Wm, const float* __restrict__ bm,
    const float* __restrict__ Wo, const float* __restrict__ bo,
    const float* __restrict__ ws_cv, const float* __restrict__ ws_a69,
    float* __restrict__ out)
{
    const int G = 8, PC = 520;
    __shared__ float pc[8 * 520];      // [a256(256) | p256(256)] per sample
    __shared__ float a69T[128 * 8];    // chunk of a69, transposed [j][sample]
    __shared__ float p40s[8 * 40];
    __shared__ float phs[8 * 40];
    __shared__ float wts[8];
    __shared__ float cps[2][8 * 84];
    const int tid  = threadIdx.x;
    const int lane = tid & 63;
    const int wv   = tid >> 6;
    const int blk  = blockIdx.x;
    const int b0   = blk * G;
    const int c0   = lane * 4;
    const int s0   = wv * 2;          // wave's 2 samples

    // ---- a256 = a69 @ W2 + b2 (8 chunks of 128 rows; last = 105) ----
    {
        float accA[2][4];
        #pragma unroll
        for (int s = 0; s < 2; ++s)
            #pragma unroll
            for (int c = 0; c < 4; ++c) accA[s][c] = 0.f;
        for (int ch = 0; ch < 8; ++ch) {
            const int j0 = ch * 128;
            const int nr = (ch == 7) ? 105 : 128;
            __syncthreads();           // protect a69T reuse
            for (int i = tid; i < 512; i += 256) {
                const int jj = i & 127, sg = i >> 7;     // sg in 0..3 -> samples 2sg,2sg+1
                if (jj < nr) {
                    const float v0 = ws_a69[(size_t)(b0 + sg * 2) * 1001 + j0 + jj];
                    const float v1 = ws_a69[(size_t)(b0 + sg * 2 + 1) * 1001 + j0 + jj];
                    *(float2*)(a69T + jj * 8 + sg * 2) = make_float2(v0, v1);
                }
            }
            __syncthreads();
            #pragma unroll 4
            for (int jj = 0; jj < nr; ++jj) {
                const float2 av = *(const float2*)(a69T + jj * 8 + s0);
                float w2v[4];
                *(float4*)w2v = *(const float4*)(W2 + (size_t)(j0 + jj) * 256 + c0);
                #pragma unroll
                for (int c = 0; c < 4; ++c) {
                    accA[0][c] = fmaf(av.x, w2v[c], accA[0][c]);
                    accA[1][c] = fmaf(av.y, w2v[c], accA[1][c]);
                }
            }
        }
        float b2v[4];
        *(float4*)b2v = *(const float4*)(b2 + c0);
        #pragma unroll
        for (int s = 0; s < 2; ++s) {
            float o[4];
            #pragma unroll
            for (int c = 0; c < 4; ++c) o[c] = accA[s][c] + b2v[c];
            *(float4*)(pc + (s0 + s) * PC + c0) = *(float4*)o;
        }
    }

    // ---- p256 = protein @ W3 + b3 (registers, 2 samples per wave) ----
    {
        float acc[2][4];
        #pragma unroll
        for (int s = 0; s < 2; ++s)
            #pragma unroll
            for (int c = 0; c < 4; ++c) acc[s][c] = 0.f;
        const float* prot = protein + (size_t)(b0 + s0) * 512;
        for (int j4 = 0; j4 < 128; ++j4) {
            float pv0[4], pv1[4];
            *(float4*)pv0 = *(const float4*)(prot + j4 * 4);
            *(float4*)pv1 = *(const float4*)(prot + 512 + j4 * 4);
            #pragma unroll
            for (int u = 0; u < 4; ++u) {
                float w3v[4];
                *(float4*)w3v = *(const float4*)(W3 + (size_t)(j4 * 4 + u) * 256 + c0);
                #pragma unroll
                for (int c = 0; c < 4; ++c) {
                    acc[0][c] = fmaf(pv0[u], w3v[c], acc[0][c]);
                    acc[1][c] = fmaf(pv1[u], w3v[c], acc[1][c]);
                }
            }
        }
        float b3v[4];
        *(float4*)b3v = *(const float4*)(b3 + c0);
        #pragma unroll
        for (int s = 0; s < 2; ++s) {
            float o[4];
            #pragma unroll
            for (int c = 0; c < 4; ++c) o[c] = acc[s][c] + b3v[c];
            *(float4*)(pc + (s0 + s) * PC + 256 + c0) = *(float4*)o;
        }
    }
    __syncthreads();

    // ---- p40 = pcat @ Wp + bp  (40 tasks: (f8 0..4, g 0..7), 8 cols each) ----
    if (tid < 40) {
        const int f8 = tid >> 3, g = tid & 7, fo = f8 * 8;
        float a8[8];
        #pragma unroll
        for (int c = 0; c < 8; ++c) a8[c] = bp[fo + c];
        for (int j4 = 0; j4 < 128; ++j4) {
            float pv[4];
            *(float4*)pv = *(float4*)(pc + g * PC + j4 * 4);
            #pragma unroll
            for (int u = 0; u < 4; ++u) {
                const int j = j4 * 4 + u;
                float wa[4], wb[4];
                *(float4*)wa = *(const float4*)(Wp + j * 40 + fo);
                *(float4*)wb = *(const float4*)(Wp + j * 40 + fo + 4);
                #pragma unroll
                for (int c = 0; c < 4; ++c) {
                    a8[c]     = fmaf(pv[u], wa[c], a8[c]);
                    a8[4 + c] = fmaf(pv[u], wb[c], a8[4 + c]);
                }
            }
        }
        *(float4*)(p40s + g * 40 + fo)     = *(float4*)a8;
        *(float4*)(p40s + g * 40 + fo + 4) = *(float4*)(a8 + 4);
    }
    __syncthreads();

    // ---- protein_h = relu(p40 @ Watt + batt) ----
    for (int it = tid; it < G * 40; it += 256) {
        const int g = it / 40, f = it - g * 40;
        float s = batt[f];
        #pragma unroll
        for (int j4 = 0; j4 < 10; ++j4) {
            float pv[4];
            *(float4*)pv = *(float4*)(p40s + g * 40 + j4 * 4);
            #pragma unroll
            for (int u = 0; u < 4; ++u)
                s = fmaf(pv[u], Watt[(j4 * 4 + u) * 40 + f], s);
        }
        phs[it] = s > 0.f ? s : 0.f;
    }
    __syncthreads();

    // ---- attention weight ----
    if (tid < G) {
        float m = 0.f;
        #pragma unroll
        for (int f4 = 0; f4 < 10; ++f4) {
            float cv[4], ph[4];
            *(float4*)cv = *(const float4*)(ws_cv + (size_t)(b0 + tid) * 40 + f4 * 4);
            *(float4*)ph = *(float4*)(phs + tid * 40 + f4 * 4);
            #pragma unroll
            for (int c = 0; c < 4; ++c) m = fmaf(cv[c], ph[c], m);
        }
        wts[tid] = tanhf(m);
    }
    __syncthreads();

    // ---- cp = [compound_vec | weights * protein_h] ----
    for (int it = tid; it < G * 80; it += 256) {
        const int g = it / 80, f = it - g * 80;
        const float v = (f < 40) ? ws_cv[(size_t)(b0 + g) * 40 + f]
                                 : wts[g] * phs[g * 40 + (f - 40)];
        cps[0][g * 84 + f] = v;
    }
    __syncthreads();

    // ---- MLP head ----
    int cb = 0;
    for (int l = 0; l < 2; ++l) {
        for (int it = tid; it < G * 80; it += 256) {
            const int g = it / 80, kk = it - g * 80;
            float s = bm[l * 80 + kk];
            #pragma unroll
            for (int j4 = 0; j4 < 20; ++j4) {
                float cv[4];
                *(float4*)cv = *(float4*)(cps[cb] + g * 84 + j4 * 4);
                #pragma unroll
                for (int u = 0; u < 4; ++u)
                    s = fmaf(cv[u], Wm[l * 6400 + (j4 * 4 + u) * 80 + kk], s);
            }
            cps[cb ^ 1][g * 84 + kk] = s > 0.f ? s : 0.f;
        }
        __syncthreads();
        cb ^= 1;
    }
    if (tid < G) {
        float s = bo[0];
        #pragma unroll
        for (int j4 = 0; j4 < 20; ++j4) {
            float cv[4], wo[4];
            *(float4*)cv = *(float4*)(cps[cb] + tid * 84 + j4 * 4);
            *(float4*)wo = *(const float4*)(Wo + j4 * 4);
            #pragma unroll
            for (int u = 0; u < 4; ++u) s = fmaf(cv[u], wo[u], s);
        }
        out[b0 + tid] = s;
    }
}

extern "C" void kernel_launch(void* const* d_in, const int* in_sizes, int n_in,
                              void* d_out, int out_size, void* d_ws, size_t ws_size,
                              hipStream_t stream) {
    const int*   atoms   = (const int*)d_in[0];
    const float* A       = (const float*)d_in[1];
    const float* A69     = (const float*)d_in[2];
    const float* protein = (const float*)d_in[3];
    const float* emb     = (const float*)d_in[4];
    const float* Wg      = (const float*)d_in[5];
    const float* bg      = (const float*)d_in[6];
    const float* Watt    = (const float*)d_in[7];
    const float* batt    = (const float*)d_in[8];
    const float* W1      = (const float*)d_in[9];
    const float* b1      = (const float*)d_in[10];
    const float* W2      = (const float*)d_in[11];
    const float* b2      = (const float*)d_in[12];
    const float* W3      = (const float*)d_in[13];
    const float* b3      = (const float*)d_in[14];
    const float* Wp      = (const float*)d_in[15];
    const float* bp      = (const float*)d_in[16];
    const float* Wm      = (const float*)d_in[17];
    const float* bm      = (const float*)d_in[18];
    const float* Wo      = (const float*)d_in[19];
    const float* bo      = (const float*)d_in[20];

    float* ws_cv  = (float*)d_ws;                  // [4096][40]
    float* ws_a69 = ws_cv + (size_t)BATCH * 40;    // [4096*1001]
    float* outp   = (float*)d_out;

    k_heavy<<<dim3(1024 + BATCH), dim3(256), 0, stream>>>(
        atoms, A, A69, emb, Wg, bg, W1, b1, ws_cv, ws_a69);
    k_tail<<<dim3(512), dim3(256), 0, stream>>>(
        protein, W2, b2, W3, b3, Wp, bp, Watt, batt, Wm, bm, Wo, bo,
        ws_cv, ws_a69, outp);
}